// Round 1
// baseline (1880.322 us; speedup 1.0000x reference)
//
#include <hip/hip_runtime.h>
#include <math.h>

#define T_SEQ 2048
#define BATCH 4
#define E_DIM 2048
#define NHEAD 16
#define HDIM 128
#define RMS_EPS 1.1920929e-07f

typedef unsigned short u16;
typedef __attribute__((ext_vector_type(8))) unsigned short u16x8;
typedef __attribute__((ext_vector_type(8))) short bf16x8;
typedef __attribute__((ext_vector_type(4))) float f32x4;

static __device__ __forceinline__ u16 f2b(float f) {
  unsigned int u = __builtin_bit_cast(unsigned int, f);
  u += 0x7fffu + ((u >> 16) & 1u);
  return (u16)(u >> 16);
}
static __device__ __forceinline__ float b2f(u16 v) {
  return __builtin_bit_cast(float, ((unsigned int)v) << 16);
}

// ---------------- fp32 -> bf16 convert ----------------
__global__ __launch_bounds__(256) void convert_f32_bf16(
    const float* __restrict__ src, u16* __restrict__ dst, int n) {
  int i = (blockIdx.x * 256 + threadIdx.x) * 4;
  if (i >= n) return;
  float4 v = *reinterpret_cast<const float4*>(src + i);
  ushort4 o;
  o.x = f2b(v.x); o.y = f2b(v.y); o.z = f2b(v.z); o.w = f2b(v.w);
  *reinterpret_cast<ushort4*>(dst + i) = o;
}

// ---------------- rope tables (double precision trig) ----------------
__global__ __launch_bounds__(256) void rope_tables_k(
    float* __restrict__ cost, float* __restrict__ sint) {
  int idx = blockIdx.x * 256 + threadIdx.x;   // T_SEQ*64 total
  int i = idx & 63, t = idx >> 6;
  double inv = pow(10000.0, -(double)i / 64.0);
  double ang = (double)t * inv;
  cost[idx] = (float)cos(ang);
  sint[idx] = (float)sin(ang);
}

// ---------------- fused rope + rmsnorm (in-place on bf16 QK) ----------------
// one wave per (b,t,h) row of 128; lane i handles pair (i, i+64)
__global__ __launch_bounds__(256) void rope_rms_k(
    u16* __restrict__ qk, const float* __restrict__ cost,
    const float* __restrict__ sint, float outscale) {
  int wave = threadIdx.x >> 6;
  int lane = threadIdx.x & 63;
  long long row = (long long)blockIdx.x * 4 + wave;   // (b*T + t)*H + h
  int th = (int)(row >> 4);                            // b*T + t
  int t = th & (T_SEQ - 1);
  u16* p = qk + row * HDIM;
  float x1 = b2f(p[lane]);
  float x2 = b2f(p[lane + 64]);
  float c = cost[t * 64 + lane];
  float s = sint[t * 64 + lane];
  float o1 = x1 * c - x2 * s;
  float o2 = x1 * s + x2 * c;
  float ss = o1 * o1 + o2 * o2;
#pragma unroll
  for (int m = 32; m >= 1; m >>= 1) ss += __shfl_xor(ss, m, 64);
  float r = rsqrtf(ss * (1.0f / 128.0f) + RMS_EPS) * outscale;
  p[lane] = f2b(o1 * r);
  p[lane + 64] = f2b(o2 * r);
}

// ---------------- V transpose: [B,T,H,D] -> per (b,h): [D][T] ----------------
__global__ __launch_bounds__(256) void transpose_v_k(
    const u16* __restrict__ V, u16* __restrict__ Vt) {
  __shared__ u16 tile[64][72];
  int t0 = blockIdx.x * 64, d0 = blockIdx.y * 64;
  int bh = blockIdx.z;                 // b*NHEAD + h
  int b = bh >> 4, h = bh & 15;
  int tid = threadIdx.x;
  int lrow = tid >> 3;                 // 0..31
  int lcol = (tid & 7) * 8;
#pragma unroll
  for (int pass = 0; pass < 2; ++pass) {
    int row = lrow + pass * 32;
    const u16* src = V + ((((long long)b * T_SEQ + t0 + row) * NHEAD + h) << 7) + d0 + lcol;
    *reinterpret_cast<u16x8*>(&tile[row][lcol]) = *reinterpret_cast<const u16x8*>(src);
  }
  __syncthreads();
#pragma unroll
  for (int pass = 0; pass < 2; ++pass) {
    int drow = (tid >> 3) + pass * 32;
    int tcol = (tid & 7) * 8;
    u16x8 o;
#pragma unroll
    for (int i = 0; i < 8; ++i) o[i] = tile[tcol + i][drow];
    u16* dst = Vt + ((long long)bh * HDIM + d0 + drow) * T_SEQ + t0 + tcol;
    *reinterpret_cast<u16x8*>(dst) = o;
  }
}

// ---------------- bf16 MFMA GEMM: C[M,N] = A[M,K] * B[K,N] ----------------
// 128x128 tile, BK=32, 256 threads (4 waves, 2x2), 4x4 16x16 tiles per wave.
// grid.z selects (B,C) pair for fused QKV; Cf!=nullptr -> fp32 output.
__global__ __launch_bounds__(256) void gemm_bf16_k(
    const u16* __restrict__ A,
    const u16* __restrict__ Bp0, const u16* __restrict__ Bp1, const u16* __restrict__ Bp2,
    u16* __restrict__ C0, u16* __restrict__ C1, u16* __restrict__ C2,
    float* __restrict__ Cf, int M, int N, int K) {
  const u16* B = blockIdx.z == 0 ? Bp0 : (blockIdx.z == 1 ? Bp1 : Bp2);
  u16* C = blockIdx.z == 0 ? C0 : (blockIdx.z == 1 ? C1 : C2);
  __shared__ u16 As[128][40];   // [m][k] pad 32->40
  __shared__ u16 Bt[128][40];   // [n][k] transposed, pad 32->40
  int tid = threadIdx.x;
  int lane = tid & 63, wave = tid >> 6;
  int wm = (wave >> 1) * 64, wn = (wave & 1) * 64;
  int m0 = blockIdx.y * 128, n0 = blockIdx.x * 128;
  int lr = lane & 15, lq = lane >> 4;
  f32x4 acc[4][4] = {};
  int a_row = tid >> 2;            // 0..63 (+64 on pass 1)
  int a_col = (tid & 3) * 8;
  int b_row = tid >> 4;            // 0..15 (+16 on pass 1)
  int b_col = (tid & 15) * 8;
  for (int kk = 0; kk < K; kk += 32) {
    __syncthreads();
#pragma unroll
    for (int pass = 0; pass < 2; ++pass) {
      int row = a_row + pass * 64;
      *reinterpret_cast<u16x8*>(&As[row][a_col]) =
          *reinterpret_cast<const u16x8*>(A + (long long)(m0 + row) * K + kk + a_col);
    }
#pragma unroll
    for (int pass = 0; pass < 2; ++pass) {
      int r = b_row + pass * 16;
      u16x8 v = *reinterpret_cast<const u16x8*>(B + (long long)(kk + r) * N + n0 + b_col);
#pragma unroll
      for (int i = 0; i < 8; ++i) Bt[b_col + i][r] = v[i];
    }
    __syncthreads();
    bf16x8 af[4], bfg[4];
#pragma unroll
    for (int mt = 0; mt < 4; ++mt)
      af[mt] = *reinterpret_cast<const bf16x8*>(&As[wm + mt * 16 + lr][lq * 8]);
#pragma unroll
    for (int nt = 0; nt < 4; ++nt)
      bfg[nt] = *reinterpret_cast<const bf16x8*>(&Bt[wn + nt * 16 + lr][lq * 8]);
#pragma unroll
    for (int mt = 0; mt < 4; ++mt)
#pragma unroll
      for (int nt = 0; nt < 4; ++nt)
        acc[mt][nt] = __builtin_amdgcn_mfma_f32_16x16x32_bf16(af[mt], bfg[nt], acc[mt][nt], 0, 0, 0);
  }
#pragma unroll
  for (int mt = 0; mt < 4; ++mt)
#pragma unroll
    for (int nt = 0; nt < 4; ++nt)
#pragma unroll
      for (int r = 0; r < 4; ++r) {
        long long row = m0 + wm + mt * 16 + lq * 4 + r;
        long long col = n0 + wn + nt * 16 + lr;
        float v = acc[mt][nt][r];
        if (Cf) Cf[row * N + col] = v;
        else C[row * N + col] = f2b(v);
      }
}

// ---------------- causal flash attention ----------------
// grid (T/64, B*H); block 256 = 4 waves; wave w owns q rows [qt*64+w*16, +16)
__global__ __launch_bounds__(256) void attn_k(
    const u16* __restrict__ Q, const u16* __restrict__ K,
    const u16* __restrict__ Vt, u16* __restrict__ Y) {
  __shared__ u16 Ks[64][136];       // [key][d] pad 128->136
  __shared__ u16 Vs[128][72];       // [d][key] pad 64->72
  __shared__ u16 Ps[4][16][72];     // per-wave P tile [q][key] pad 64->72
  int qt = blockIdx.x, bh = blockIdx.y;
  int b = bh >> 4, h = bh & 15;
  int tid = threadIdx.x, lane = tid & 63, wave = tid >> 6;
  int lr = lane & 15, lq = lane >> 4;
  // Q fragments (A-layout), Q already scaled by 1/sqrt(D) in rope kernel
  bf16x8 aq[4];
  {
    int qrow = qt * 64 + wave * 16 + lr;
    const u16* qp = Q + (((long long)b * T_SEQ + qrow) * NHEAD + h) * HDIM;
#pragma unroll
    for (int kt = 0; kt < 4; ++kt)
      aq[kt] = *reinterpret_cast<const bf16x8*>(qp + kt * 32 + lq * 8);
  }
  float m_r[4], l_r[4];
#pragma unroll
  for (int r = 0; r < 4; ++r) { m_r[r] = -INFINITY; l_r[r] = 0.f; }
  f32x4 o[8] = {};
  for (int j = 0; j <= qt; ++j) {
    __syncthreads();
#pragma unroll
    for (int rr = 0; rr < 4; ++rr) {
      int f = tid * 8 + rr * 2048;
      int krow = f >> 7, kcol = f & 127;
      *reinterpret_cast<u16x8*>(&Ks[krow][kcol]) = *reinterpret_cast<const u16x8*>(
          K + (((long long)b * T_SEQ + j * 64 + krow) * NHEAD + h) * HDIM + kcol);
      int vrow = f >> 6, vcol = f & 63;
      *reinterpret_cast<u16x8*>(&Vs[vrow][vcol]) = *reinterpret_cast<const u16x8*>(
          Vt + ((long long)bh * HDIM + vrow) * T_SEQ + j * 64 + vcol);
    }
    __syncthreads();
    // S = Q K^T  (16 q x 64 keys per wave)
    f32x4 s[4];
#pragma unroll
    for (int nt = 0; nt < 4; ++nt) {
      s[nt] = 0.f;
#pragma unroll
      for (int kt = 0; kt < 4; ++kt) {
        bf16x8 bk = *reinterpret_cast<const bf16x8*>(&Ks[nt * 16 + lr][kt * 32 + lq * 8]);
        s[nt] = __builtin_amdgcn_mfma_f32_16x16x32_bf16(aq[kt], bk, s[nt], 0, 0, 0);
      }
    }
    if (j == qt) {   // causal mask, diagonal tile only
#pragma unroll
      for (int nt = 0; nt < 4; ++nt) {
        int kg = nt * 16 + lr;
#pragma unroll
        for (int r = 0; r < 4; ++r) {
          int qg = wave * 16 + lq * 4 + r;
          if (kg > qg) s[nt][r] = -INFINITY;
        }
      }
    }
    // online softmax (rows live in 16-lane groups)
    float pr[4][4];
#pragma unroll
    for (int r = 0; r < 4; ++r) {
      float mx = fmaxf(fmaxf(s[0][r], s[1][r]), fmaxf(s[2][r], s[3][r]));
#pragma unroll
      for (int mstep = 8; mstep >= 1; mstep >>= 1) mx = fmaxf(mx, __shfl_xor(mx, mstep, 16));
      float mn = fmaxf(m_r[r], mx);
      float alpha = __expf(m_r[r] - mn);
      m_r[r] = mn;
      float sum = 0.f;
#pragma unroll
      for (int nt = 0; nt < 4; ++nt) {
        float p = __expf(s[nt][r] - mn);
        pr[nt][r] = p;
        sum += p;
      }
#pragma unroll
      for (int mstep = 8; mstep >= 1; mstep >>= 1) sum += __shfl_xor(sum, mstep, 16);
      l_r[r] = l_r[r] * alpha + sum;
#pragma unroll
      for (int dt = 0; dt < 8; ++dt) o[dt][r] *= alpha;
    }
    // P: C-layout -> A-layout via per-wave LDS (in-order DS within a wave)
#pragma unroll
    for (int nt = 0; nt < 4; ++nt)
#pragma unroll
      for (int r = 0; r < 4; ++r)
        Ps[wave][lq * 4 + r][nt * 16 + lr] = f2b(pr[nt][r]);
    bf16x8 ap[2];
#pragma unroll
    for (int kh = 0; kh < 2; ++kh)
      ap[kh] = *reinterpret_cast<const bf16x8*>(&Ps[wave][lr][kh * 32 + lq * 8]);
#pragma unroll
    for (int dt = 0; dt < 8; ++dt)
#pragma unroll
      for (int kh = 0; kh < 2; ++kh) {
        bf16x8 bv = *reinterpret_cast<const bf16x8*>(&Vs[dt * 16 + lr][kh * 32 + lq * 8]);
        o[dt] = __builtin_amdgcn_mfma_f32_16x16x32_bf16(ap[kh], bv, o[dt], 0, 0, 0);
      }
  }
  // epilogue: Y[b,t,h,d] bf16
  int qbase = qt * 64 + wave * 16 + lq * 4;
#pragma unroll
  for (int r = 0; r < 4; ++r) {
    float inv = 1.0f / l_r[r];
    u16* yp = Y + (((long long)b * T_SEQ + qbase + r) * NHEAD + h) * HDIM;
#pragma unroll
    for (int dt = 0; dt < 8; ++dt)
      yp[dt * 16 + lr] = f2b(o[dt][r] * inv);
  }
}

extern "C" void kernel_launch(void* const* d_in, const int* in_sizes, int n_in,
                              void* d_out, int out_size, void* d_ws, size_t ws_size,
                              hipStream_t stream) {
  (void)in_sizes; (void)n_in; (void)out_size; (void)ws_size;
  const float* x  = (const float*)d_in[0];
  const float* wq = (const float*)d_in[1];
  const float* wk = (const float*)d_in[2];
  const float* wv = (const float*)d_in[3];
  const float* wo = (const float*)d_in[4];
  float* out = (float*)d_out;

  char* ws = (char*)d_ws;
  size_t off = 0;
  auto alloc = [&](size_t bytes) {
    char* p = ws + off;
    off += (bytes + 255) & ~(size_t)255;
    return p;
  };
  const size_t NTOK = (size_t)BATCH * T_SEQ;      // 8192
  const size_t XE = NTOK * E_DIM;                  // 16,777,216
  const size_t WE = (size_t)E_DIM * E_DIM;         // 4,194,304

  u16* xb  = (u16*)alloc(XE * 2);
  u16* wqb = (u16*)alloc(WE * 2);
  u16* wkb = (u16*)alloc(WE * 2);
  u16* wvb = (u16*)alloc(WE * 2);
  u16* wob = (u16*)alloc(WE * 2);
  u16* Qb  = (u16*)alloc(XE * 2);
  u16* Kb  = (u16*)alloc(XE * 2);
  u16* Vb  = (u16*)alloc(XE * 2);
  u16* Vt  = (u16*)alloc(XE * 2);
  u16* Yb  = (u16*)alloc(XE * 2);
  float* cost = (float*)alloc((size_t)T_SEQ * 64 * 4);
  float* sint = (float*)alloc((size_t)T_SEQ * 64 * 4);

  convert_f32_bf16<<<XE / 1024, 256, 0, stream>>>(x, xb, (int)XE);
  convert_f32_bf16<<<WE / 1024, 256, 0, stream>>>(wq, wqb, (int)WE);
  convert_f32_bf16<<<WE / 1024, 256, 0, stream>>>(wk, wkb, (int)WE);
  convert_f32_bf16<<<WE / 1024, 256, 0, stream>>>(wv, wvb, (int)WE);
  convert_f32_bf16<<<WE / 1024, 256, 0, stream>>>(wo, wob, (int)WE);
  rope_tables_k<<<(T_SEQ * 64) / 256, 256, 0, stream>>>(cost, sint);

  // QKV projections, fused over grid.z
  dim3 gq(E_DIM / 128, NTOK / 128, 3);
  gemm_bf16_k<<<gq, 256, 0, stream>>>(xb, wqb, wkb, wvb, Qb, Kb, Vb, nullptr,
                                      (int)NTOK, E_DIM, E_DIM);

  // rope + rms; fold softmax scale 1/sqrt(128) into Q
  rope_rms_k<<<(unsigned)(NTOK * NHEAD / 4), 256, 0, stream>>>(Qb, cost, sint, 0.08838834764831845f);
  rope_rms_k<<<(unsigned)(NTOK * NHEAD / 4), 256, 0, stream>>>(Kb, cost, sint, 1.0f);

  dim3 gt(T_SEQ / 64, HDIM / 64, BATCH * NHEAD);
  transpose_v_k<<<gt, 256, 0, stream>>>(Vb, Vt);

  dim3 ga(T_SEQ / 64, BATCH * NHEAD);
  attn_k<<<ga, 256, 0, stream>>>(Qb, Kb, Vt, Yb);

  // output projection -> fp32 d_out
  dim3 go(E_DIM / 128, NTOK / 128, 1);
  gemm_bf16_k<<<go, 256, 0, stream>>>(Yb, wob, wob, wob, nullptr, nullptr, nullptr, out,
                                      (int)NTOK, E_DIM, E_DIM);
}

// Round 2
// 1125.239 us; speedup vs baseline: 1.6710x; 1.6710x over previous
//
#include <hip/hip_runtime.h>
#include <math.h>

#define T_SEQ 2048
#define BATCH 4
#define E_DIM 2048
#define NHEAD 16
#define HDIM 128
#define RMS_EPS 1.1920929e-07f

typedef unsigned short u16;
typedef __attribute__((ext_vector_type(8))) unsigned short u16x8;
typedef __attribute__((ext_vector_type(8))) short bf16x8;
typedef __attribute__((ext_vector_type(4))) float f32x4;

typedef const __attribute__((address_space(1))) unsigned int g_u32;
typedef __attribute__((address_space(3))) unsigned int l_u32;

static __device__ __forceinline__ u16 f2b(float f) {
  unsigned int u = __builtin_bit_cast(unsigned int, f);
  u += 0x7fffu + ((u >> 16) & 1u);
  return (u16)(u >> 16);
}
static __device__ __forceinline__ float b2f(u16 v) {
  return __builtin_bit_cast(float, ((unsigned int)v) << 16);
}

// ---------------- fp32 -> bf16 convert (x only) ----------------
__global__ __launch_bounds__(256) void convert_f32_bf16(
    const float* __restrict__ src, u16* __restrict__ dst, int n) {
  int i = (blockIdx.x * 256 + threadIdx.x) * 4;
  if (i >= n) return;
  float4 v = *reinterpret_cast<const float4*>(src + i);
  ushort4 o;
  o.x = f2b(v.x); o.y = f2b(v.y); o.z = f2b(v.z); o.w = f2b(v.w);
  *reinterpret_cast<ushort4*>(dst + i) = o;
}

// ---------------- fused fp32->bf16 convert + transpose: Wt[n][k]=W[k][n] ----
__global__ __launch_bounds__(256) void convt_w_k(
    const float* __restrict__ W, u16* __restrict__ Wt) {
  __shared__ u16 tile[64][72];
  int c0 = blockIdx.x * 64;   // source col block -> dest row block
  int r0 = blockIdx.y * 64;   // source row block -> dest col block
  int tid = threadIdx.x;
  int lrow = tid >> 2;        // 0..63
  int lcol = (tid & 3) * 16;
#pragma unroll
  for (int i = 0; i < 4; ++i) {
    float4 v = *reinterpret_cast<const float4*>(
        W + (long long)(r0 + lrow) * E_DIM + c0 + lcol + i * 4);
    tile[lrow][lcol + i * 4 + 0] = f2b(v.x);
    tile[lrow][lcol + i * 4 + 1] = f2b(v.y);
    tile[lrow][lcol + i * 4 + 2] = f2b(v.z);
    tile[lrow][lcol + i * 4 + 3] = f2b(v.w);
  }
  __syncthreads();
  int wrow = tid >> 2;        // dest row offset within block (source col)
  int wcol = (tid & 3) * 16;  // dest col offset (source row)
  u16 o[16];
#pragma unroll
  for (int i = 0; i < 16; ++i) o[i] = tile[wcol + i][wrow];
  u16* dst = Wt + (long long)(c0 + wrow) * E_DIM + r0 + wcol;
  *reinterpret_cast<u16x8*>(dst)     = *reinterpret_cast<u16x8*>(&o[0]);
  *reinterpret_cast<u16x8*>(dst + 8) = *reinterpret_cast<u16x8*>(&o[8]);
}

// ---------------- rope tables (double precision trig) ----------------
__global__ __launch_bounds__(256) void rope_tables_k(
    float* __restrict__ cost, float* __restrict__ sint) {
  int idx = blockIdx.x * 256 + threadIdx.x;   // T_SEQ*64 total
  int i = idx & 63, t = idx >> 6;
  double inv = pow(10000.0, -(double)i / 64.0);
  double ang = (double)t * inv;
  cost[idx] = (float)cos(ang);
  sint[idx] = (float)sin(ang);
}

// ---------------- fused rope + rmsnorm (in-place on bf16 QK) ----------------
__global__ __launch_bounds__(256) void rope_rms_k(
    u16* __restrict__ qk, const float* __restrict__ cost,
    const float* __restrict__ sint, float outscale) {
  int wave = threadIdx.x >> 6;
  int lane = threadIdx.x & 63;
  long long row = (long long)blockIdx.x * 4 + wave;   // (b*T + t)*H + h
  int th = (int)(row >> 4);                            // b*T + t
  int t = th & (T_SEQ - 1);
  u16* p = qk + row * HDIM;
  float x1 = b2f(p[lane]);
  float x2 = b2f(p[lane + 64]);
  float c = cost[t * 64 + lane];
  float s = sint[t * 64 + lane];
  float o1 = x1 * c - x2 * s;
  float o2 = x1 * s + x2 * c;
  float ss = o1 * o1 + o2 * o2;
#pragma unroll
  for (int m = 32; m >= 1; m >>= 1) ss += __shfl_xor(ss, m, 64);
  float r = rsqrtf(ss * (1.0f / 128.0f) + RMS_EPS) * outscale;
  p[lane] = f2b(o1 * r);
  p[lane + 64] = f2b(o2 * r);
}

// ---------------- V transpose: [B,T,H,D] -> per (b,h): [D][T] ----------------
__global__ __launch_bounds__(256) void transpose_v_k(
    const u16* __restrict__ V, u16* __restrict__ Vt) {
  __shared__ u16 tile[64][72];
  int t0 = blockIdx.x * 64, d0 = blockIdx.y * 64;
  int bh = blockIdx.z;                 // b*NHEAD + h
  int b = bh >> 4, h = bh & 15;
  int tid = threadIdx.x;
  int lrow = tid >> 3;                 // 0..31
  int lcol = (tid & 7) * 8;
#pragma unroll
  for (int pass = 0; pass < 2; ++pass) {
    int row = lrow + pass * 32;
    const u16* src = V + ((((long long)b * T_SEQ + t0 + row) * NHEAD + h) << 7) + d0 + lcol;
    *reinterpret_cast<u16x8*>(&tile[row][lcol]) = *reinterpret_cast<const u16x8*>(src);
  }
  __syncthreads();
#pragma unroll
  for (int pass = 0; pass < 2; ++pass) {
    int drow = (tid >> 3) + pass * 32;
    int tcol = (tid & 7) * 8;
    u16x8 o;
#pragma unroll
    for (int i = 0; i < 8; ++i) o[i] = tile[tcol + i][drow];
    u16* dst = Vt + ((long long)bh * HDIM + d0 + drow) * T_SEQ + t0 + tcol;
    *reinterpret_cast<u16x8*>(dst) = o;
  }
}

// ---------------- bf16 MFMA GEMM (m97 structure): C[M,N] = A[M,K] * Bt[N,K]^T
// 128x128 tile, BK=32, 4 waves 2x2, 4x4 16x16 acc/wave.
// global_load_lds width=16, unpadded [row][32] LDS, xor k-slot swizzle.
__global__ __launch_bounds__(256) void gemm_bt_k(
    const u16* __restrict__ A,
    const u16* __restrict__ Bt0, const u16* __restrict__ Bt1, const u16* __restrict__ Bt2,
    u16* __restrict__ C0, u16* __restrict__ C1, u16* __restrict__ C2,
    float* __restrict__ Cf, int M, int N, int K) {
  const u16* Bt = blockIdx.z == 0 ? Bt0 : (blockIdx.z == 1 ? Bt1 : Bt2);
  u16* C = blockIdx.z == 0 ? C0 : (blockIdx.z == 1 ? C1 : C2);
  __shared__ u16 As[128 * 32];
  __shared__ u16 Bs[128 * 32];
  int tid = threadIdx.x;
  int lane = tid & 63, wave = tid >> 6;
  int wm = (wave >> 1) * 64, wn = (wave & 1) * 64;
  int m0 = blockIdx.y * 128, n0 = blockIdx.x * 128;
  int lr = lane & 15, lq = lane >> 4;
  f32x4 acc[4][4] = {};
  int srow = tid >> 2;          // 0..63 (+64 on pass 1)
  int sslot = tid & 3;

  for (int kk = 0; kk < K; kk += 32) {
    __syncthreads();
#pragma unroll
    for (int p = 0; p < 2; ++p) {
      int row = srow + p * 64;
      int kg = (sslot - (row >> 1)) & 3;     // xor-swizzle: slot s holds k-group g
      __builtin_amdgcn_global_load_lds(
          (g_u32*)(A + (long long)(m0 + row) * K + kk + kg * 8),
          (l_u32*)(As + p * 2048 + wave * 512), 16, 0, 0);
      __builtin_amdgcn_global_load_lds(
          (g_u32*)(Bt + (long long)(n0 + row) * K + kk + kg * 8),
          (l_u32*)(Bs + p * 2048 + wave * 512), 16, 0, 0);
    }
    __syncthreads();
    bf16x8 af[4], bfg[4];
#pragma unroll
    for (int mt = 0; mt < 4; ++mt) {
      int r = wm + mt * 16 + lr;
      int s = (lq + (r >> 1)) & 3;
      af[mt] = *reinterpret_cast<const bf16x8*>(&As[r * 32 + s * 8]);
    }
#pragma unroll
    for (int nt = 0; nt < 4; ++nt) {
      int r = wn + nt * 16 + lr;
      int s = (lq + (r >> 1)) & 3;
      bfg[nt] = *reinterpret_cast<const bf16x8*>(&Bs[r * 32 + s * 8]);
    }
#pragma unroll
    for (int mt = 0; mt < 4; ++mt)
#pragma unroll
      for (int nt = 0; nt < 4; ++nt)
        acc[mt][nt] = __builtin_amdgcn_mfma_f32_16x16x32_bf16(af[mt], bfg[nt], acc[mt][nt], 0, 0, 0);
  }
#pragma unroll
  for (int mt = 0; mt < 4; ++mt)
#pragma unroll
    for (int nt = 0; nt < 4; ++nt)
#pragma unroll
      for (int r = 0; r < 4; ++r) {
        long long row = m0 + wm + mt * 16 + lq * 4 + r;
        long long col = n0 + wn + nt * 16 + lr;
        float v = acc[mt][nt][r];
        if (Cf) Cf[row * N + col] = v;
        else C[row * N + col] = f2b(v);
      }
}

// ---------------- causal flash attention ----------------
__global__ __launch_bounds__(256) void attn_k(
    const u16* __restrict__ Q, const u16* __restrict__ K,
    const u16* __restrict__ Vt, u16* __restrict__ Y) {
  __shared__ u16 Ks[64][136];       // [key][d] pad 128->136
  __shared__ u16 Vs[128][72];       // [d][key] pad 64->72
  __shared__ u16 Ps[4][16][72];     // per-wave P tile [q][key] pad 64->72
  int qt = blockIdx.x, bh = blockIdx.y;
  int b = bh >> 4, h = bh & 15;
  int tid = threadIdx.x, lane = tid & 63, wave = tid >> 6;
  int lr = lane & 15, lq = lane >> 4;
  bf16x8 aq[4];
  {
    int qrow = qt * 64 + wave * 16 + lr;
    const u16* qp = Q + (((long long)b * T_SEQ + qrow) * NHEAD + h) * HDIM;
#pragma unroll
    for (int kt = 0; kt < 4; ++kt)
      aq[kt] = *reinterpret_cast<const bf16x8*>(qp + kt * 32 + lq * 8);
  }
  float m_r[4], l_r[4];
#pragma unroll
  for (int r = 0; r < 4; ++r) { m_r[r] = -INFINITY; l_r[r] = 0.f; }
  f32x4 o[8] = {};
  for (int j = 0; j <= qt; ++j) {
    __syncthreads();
#pragma unroll
    for (int rr = 0; rr < 4; ++rr) {
      int f = tid * 8 + rr * 2048;
      int krow = f >> 7, kcol = f & 127;
      *reinterpret_cast<u16x8*>(&Ks[krow][kcol]) = *reinterpret_cast<const u16x8*>(
          K + (((long long)b * T_SEQ + j * 64 + krow) * NHEAD + h) * HDIM + kcol);
      int vrow = f >> 6, vcol = f & 63;
      *reinterpret_cast<u16x8*>(&Vs[vrow][vcol]) = *reinterpret_cast<const u16x8*>(
          Vt + ((long long)bh * HDIM + vrow) * T_SEQ + j * 64 + vcol);
    }
    __syncthreads();
    f32x4 s[4];
#pragma unroll
    for (int nt = 0; nt < 4; ++nt) {
      s[nt] = 0.f;
#pragma unroll
      for (int kt = 0; kt < 4; ++kt) {
        bf16x8 bk = *reinterpret_cast<const bf16x8*>(&Ks[nt * 16 + lr][kt * 32 + lq * 8]);
        s[nt] = __builtin_amdgcn_mfma_f32_16x16x32_bf16(aq[kt], bk, s[nt], 0, 0, 0);
      }
    }
    if (j == qt) {
#pragma unroll
      for (int nt = 0; nt < 4; ++nt) {
        int kg = nt * 16 + lr;
#pragma unroll
        for (int r = 0; r < 4; ++r) {
          int qg = wave * 16 + lq * 4 + r;
          if (kg > qg) s[nt][r] = -INFINITY;
        }
      }
    }
    float pr[4][4];
#pragma unroll
    for (int r = 0; r < 4; ++r) {
      float mx = fmaxf(fmaxf(s[0][r], s[1][r]), fmaxf(s[2][r], s[3][r]));
#pragma unroll
      for (int mstep = 8; mstep >= 1; mstep >>= 1) mx = fmaxf(mx, __shfl_xor(mx, mstep, 16));
      float mn = fmaxf(m_r[r], mx);
      float alpha = __expf(m_r[r] - mn);
      m_r[r] = mn;
      float sum = 0.f;
#pragma unroll
      for (int nt = 0; nt < 4; ++nt) {
        float p = __expf(s[nt][r] - mn);
        pr[nt][r] = p;
        sum += p;
      }
#pragma unroll
      for (int mstep = 8; mstep >= 1; mstep >>= 1) sum += __shfl_xor(sum, mstep, 16);
      l_r[r] = l_r[r] * alpha + sum;
#pragma unroll
      for (int dt = 0; dt < 8; ++dt) o[dt][r] *= alpha;
    }
#pragma unroll
    for (int nt = 0; nt < 4; ++nt)
#pragma unroll
      for (int r = 0; r < 4; ++r)
        Ps[wave][lq * 4 + r][nt * 16 + lr] = f2b(pr[nt][r]);
    bf16x8 ap[2];
#pragma unroll
    for (int kh = 0; kh < 2; ++kh)
      ap[kh] = *reinterpret_cast<const bf16x8*>(&Ps[wave][lr][kh * 32 + lq * 8]);
#pragma unroll
    for (int dt = 0; dt < 8; ++dt)
#pragma unroll
      for (int kh = 0; kh < 2; ++kh) {
        bf16x8 bv = *reinterpret_cast<const bf16x8*>(&Vs[dt * 16 + lr][kh * 32 + lq * 8]);
        o[dt] = __builtin_amdgcn_mfma_f32_16x16x32_bf16(ap[kh], bv, o[dt], 0, 0, 0);
      }
  }
  int qbase = qt * 64 + wave * 16 + lq * 4;
#pragma unroll
  for (int r = 0; r < 4; ++r) {
    float inv = 1.0f / l_r[r];
    u16* yp = Y + (((long long)b * T_SEQ + qbase + r) * NHEAD + h) * HDIM;
#pragma unroll
    for (int dt = 0; dt < 8; ++dt)
      yp[dt * 16 + lr] = f2b(o[dt][r] * inv);
  }
}

extern "C" void kernel_launch(void* const* d_in, const int* in_sizes, int n_in,
                              void* d_out, int out_size, void* d_ws, size_t ws_size,
                              hipStream_t stream) {
  (void)in_sizes; (void)n_in; (void)out_size; (void)ws_size;
  const float* x  = (const float*)d_in[0];
  const float* wq = (const float*)d_in[1];
  const float* wk = (const float*)d_in[2];
  const float* wv = (const float*)d_in[3];
  const float* wo = (const float*)d_in[4];
  float* out = (float*)d_out;

  char* ws = (char*)d_ws;
  size_t off = 0;
  auto alloc = [&](size_t bytes) {
    char* p = ws + off;
    off += (bytes + 255) & ~(size_t)255;
    return p;
  };
  const size_t NTOK = (size_t)BATCH * T_SEQ;      // 8192
  const size_t XE = NTOK * E_DIM;                  // 16,777,216
  const size_t WE = (size_t)E_DIM * E_DIM;         // 4,194,304

  u16* xb  = (u16*)alloc(XE * 2);
  u16* wqt = (u16*)alloc(WE * 2);
  u16* wkt = (u16*)alloc(WE * 2);
  u16* wvt = (u16*)alloc(WE * 2);
  u16* wot = (u16*)alloc(WE * 2);
  u16* Qb  = (u16*)alloc(XE * 2);
  u16* Kb  = (u16*)alloc(XE * 2);
  u16* Vb  = (u16*)alloc(XE * 2);
  u16* Vt  = (u16*)alloc(XE * 2);
  u16* Yb  = (u16*)alloc(XE * 2);
  float* cost = (float*)alloc((size_t)T_SEQ * 64 * 4);
  float* sint = (float*)alloc((size_t)T_SEQ * 64 * 4);

  convert_f32_bf16<<<XE / 1024, 256, 0, stream>>>(x, xb, (int)XE);
  dim3 gw(E_DIM / 64, E_DIM / 64);
  convt_w_k<<<gw, 256, 0, stream>>>(wq, wqt);
  convt_w_k<<<gw, 256, 0, stream>>>(wk, wkt);
  convt_w_k<<<gw, 256, 0, stream>>>(wv, wvt);
  convt_w_k<<<gw, 256, 0, stream>>>(wo, wot);
  rope_tables_k<<<(T_SEQ * 64) / 256, 256, 0, stream>>>(cost, sint);

  // QKV projections, fused over grid.z
  dim3 gq(E_DIM / 128, NTOK / 128, 3);
  gemm_bt_k<<<gq, 256, 0, stream>>>(xb, wqt, wkt, wvt, Qb, Kb, Vb, nullptr,
                                    (int)NTOK, E_DIM, E_DIM);

  // rope + rms; fold softmax scale 1/sqrt(128) into Q
  rope_rms_k<<<(unsigned)(NTOK * NHEAD / 4), 256, 0, stream>>>(Qb, cost, sint, 0.08838834764831845f);
  rope_rms_k<<<(unsigned)(NTOK * NHEAD / 4), 256, 0, stream>>>(Kb, cost, sint, 1.0f);

  dim3 gt(T_SEQ / 64, HDIM / 64, BATCH * NHEAD);
  transpose_v_k<<<gt, 256, 0, stream>>>(Vb, Vt);

  dim3 ga(T_SEQ / 64, BATCH * NHEAD);
  attn_k<<<ga, 256, 0, stream>>>(Qb, Kb, Vt, Yb);

  // output projection -> fp32 d_out
  dim3 go(E_DIM / 128, NTOK / 128, 1);
  gemm_bt_k<<<go, 256, 0, stream>>>(Yb, wot, wot, wot, nullptr, nullptr, nullptr, out,
                                    (int)NTOK, E_DIM, E_DIM);
}

// Round 3
// 912.786 us; speedup vs baseline: 2.0600x; 1.2328x over previous
//
#include <hip/hip_runtime.h>
#include <math.h>

#define T_SEQ 2048
#define BATCH 4
#define E_DIM 2048
#define NHEAD 16
#define HDIM 128
#define RMS_EPS 1.1920929e-07f

typedef unsigned short u16;
typedef __attribute__((ext_vector_type(8))) unsigned short u16x8;
typedef __attribute__((ext_vector_type(8))) short bf16x8;
typedef __attribute__((ext_vector_type(4))) float f32x4;

typedef const __attribute__((address_space(1))) unsigned int g_u32;
typedef __attribute__((address_space(3))) unsigned int l_u32;

static __device__ __forceinline__ u16 f2b(float f) {
  unsigned int u = __builtin_bit_cast(unsigned int, f);
  u += 0x7fffu + ((u >> 16) & 1u);
  return (u16)(u >> 16);
}
static __device__ __forceinline__ float b2f(u16 v) {
  return __builtin_bit_cast(float, ((unsigned int)v) << 16);
}

// ---------------- fp32 -> bf16 convert (x only) ----------------
__global__ __launch_bounds__(256) void convert_f32_bf16(
    const float* __restrict__ src, u16* __restrict__ dst, int n) {
  int i = (blockIdx.x * 256 + threadIdx.x) * 4;
  if (i >= n) return;
  float4 v = *reinterpret_cast<const float4*>(src + i);
  ushort4 o;
  o.x = f2b(v.x); o.y = f2b(v.y); o.z = f2b(v.z); o.w = f2b(v.w);
  *reinterpret_cast<ushort4*>(dst + i) = o;
}

// ---------------- fused fp32->bf16 convert + transpose: Wt[n][k]=W[k][n] ----
__global__ __launch_bounds__(256) void convt_w_k(
    const float* __restrict__ W, u16* __restrict__ Wt) {
  __shared__ u16 tile[64][72];
  int c0 = blockIdx.x * 64;
  int r0 = blockIdx.y * 64;
  int tid = threadIdx.x;
  int lrow = tid >> 2;
  int lcol = (tid & 3) * 16;
#pragma unroll
  for (int i = 0; i < 4; ++i) {
    float4 v = *reinterpret_cast<const float4*>(
        W + (long long)(r0 + lrow) * E_DIM + c0 + lcol + i * 4);
    tile[lrow][lcol + i * 4 + 0] = f2b(v.x);
    tile[lrow][lcol + i * 4 + 1] = f2b(v.y);
    tile[lrow][lcol + i * 4 + 2] = f2b(v.z);
    tile[lrow][lcol + i * 4 + 3] = f2b(v.w);
  }
  __syncthreads();
  int wrow = tid >> 2;
  int wcol = (tid & 3) * 16;
  u16 o[16];
#pragma unroll
  for (int i = 0; i < 16; ++i) o[i] = tile[wcol + i][wrow];
  u16* dst = Wt + (long long)(c0 + wrow) * E_DIM + r0 + wcol;
  *reinterpret_cast<u16x8*>(dst)     = *reinterpret_cast<u16x8*>(&o[0]);
  *reinterpret_cast<u16x8*>(dst + 8) = *reinterpret_cast<u16x8*>(&o[8]);
}

// ---------------- rope tables (double precision trig) ----------------
__global__ __launch_bounds__(256) void rope_tables_k(
    float* __restrict__ cost, float* __restrict__ sint) {
  int idx = blockIdx.x * 256 + threadIdx.x;
  int i = idx & 63, t = idx >> 6;
  double inv = pow(10000.0, -(double)i / 64.0);
  double ang = (double)t * inv;
  cost[idx] = (float)cos(ang);
  sint[idx] = (float)sin(ang);
}

// ---------------- fused rope + rmsnorm (in-place on bf16 QK) ----------------
__global__ __launch_bounds__(256) void rope_rms_k(
    u16* __restrict__ qk, const float* __restrict__ cost,
    const float* __restrict__ sint, float outscale) {
  int wave = threadIdx.x >> 6;
  int lane = threadIdx.x & 63;
  long long row = (long long)blockIdx.x * 4 + wave;
  int th = (int)(row >> 4);
  int t = th & (T_SEQ - 1);
  u16* p = qk + row * HDIM;
  float x1 = b2f(p[lane]);
  float x2 = b2f(p[lane + 64]);
  float c = cost[t * 64 + lane];
  float s = sint[t * 64 + lane];
  float o1 = x1 * c - x2 * s;
  float o2 = x1 * s + x2 * c;
  float ss = o1 * o1 + o2 * o2;
#pragma unroll
  for (int m = 32; m >= 1; m >>= 1) ss += __shfl_xor(ss, m, 64);
  float r = rsqrtf(ss * (1.0f / 128.0f) + RMS_EPS) * outscale;
  p[lane] = f2b(o1 * r);
  p[lane + 64] = f2b(o2 * r);
}

// ---------------- V transpose: [B,T,H,D] -> per (b,h): [D][T] ----------------
__global__ __launch_bounds__(256) void transpose_v_k(
    const u16* __restrict__ V, u16* __restrict__ Vt) {
  __shared__ u16 tile[64][72];
  int t0 = blockIdx.x * 64, d0 = blockIdx.y * 64;
  int bh = blockIdx.z;
  int b = bh >> 4, h = bh & 15;
  int tid = threadIdx.x;
  int lrow = tid >> 3;
  int lcol = (tid & 7) * 8;
#pragma unroll
  for (int pass = 0; pass < 2; ++pass) {
    int row = lrow + pass * 32;
    const u16* src = V + ((((long long)b * T_SEQ + t0 + row) * NHEAD + h) << 7) + d0 + lcol;
    *reinterpret_cast<u16x8*>(&tile[row][lcol]) = *reinterpret_cast<const u16x8*>(src);
  }
  __syncthreads();
#pragma unroll
  for (int pass = 0; pass < 2; ++pass) {
    int drow = (tid >> 3) + pass * 32;
    int tcol = (tid & 7) * 8;
    u16x8 o;
#pragma unroll
    for (int i = 0; i < 8; ++i) o[i] = tile[tcol + i][drow];
    u16* dst = Vt + ((long long)bh * HDIM + d0 + drow) * T_SEQ + t0 + tcol;
    *reinterpret_cast<u16x8*>(dst) = o;
  }
}

// ---------------- bf16 MFMA GEMM (m97 structure) ----------------
__global__ __launch_bounds__(256) void gemm_bt_k(
    const u16* __restrict__ A,
    const u16* __restrict__ Bt0, const u16* __restrict__ Bt1, const u16* __restrict__ Bt2,
    u16* __restrict__ C0, u16* __restrict__ C1, u16* __restrict__ C2,
    float* __restrict__ Cf, int M, int N, int K) {
  const u16* Bt = blockIdx.z == 0 ? Bt0 : (blockIdx.z == 1 ? Bt1 : Bt2);
  u16* C = blockIdx.z == 0 ? C0 : (blockIdx.z == 1 ? C1 : C2);
  __shared__ u16 As[128 * 32];
  __shared__ u16 Bs[128 * 32];
  int tid = threadIdx.x;
  int lane = tid & 63, wave = tid >> 6;
  int wm = (wave >> 1) * 64, wn = (wave & 1) * 64;
  int m0 = blockIdx.y * 128, n0 = blockIdx.x * 128;
  int lr = lane & 15, lq = lane >> 4;
  f32x4 acc[4][4] = {};
  int srow = tid >> 2;
  int sslot = tid & 3;

  for (int kk = 0; kk < K; kk += 32) {
    __syncthreads();
#pragma unroll
    for (int p = 0; p < 2; ++p) {
      int row = srow + p * 64;
      int kg = (sslot - (row >> 1)) & 3;
      __builtin_amdgcn_global_load_lds(
          (g_u32*)(A + (long long)(m0 + row) * K + kk + kg * 8),
          (l_u32*)(As + p * 2048 + wave * 512), 16, 0, 0);
      __builtin_amdgcn_global_load_lds(
          (g_u32*)(Bt + (long long)(n0 + row) * K + kk + kg * 8),
          (l_u32*)(Bs + p * 2048 + wave * 512), 16, 0, 0);
    }
    __syncthreads();
    bf16x8 af[4], bfg[4];
#pragma unroll
    for (int mt = 0; mt < 4; ++mt) {
      int r = wm + mt * 16 + lr;
      int s = (lq + (r >> 1)) & 3;
      af[mt] = *reinterpret_cast<const bf16x8*>(&As[r * 32 + s * 8]);
    }
#pragma unroll
    for (int nt = 0; nt < 4; ++nt) {
      int r = wn + nt * 16 + lr;
      int s = (lq + (r >> 1)) & 3;
      bfg[nt] = *reinterpret_cast<const bf16x8*>(&Bs[r * 32 + s * 8]);
    }
#pragma unroll
    for (int mt = 0; mt < 4; ++mt)
#pragma unroll
      for (int nt = 0; nt < 4; ++nt)
        acc[mt][nt] = __builtin_amdgcn_mfma_f32_16x16x32_bf16(af[mt], bfg[nt], acc[mt][nt], 0, 0, 0);
  }
#pragma unroll
  for (int mt = 0; mt < 4; ++mt)
#pragma unroll
    for (int nt = 0; nt < 4; ++nt)
#pragma unroll
      for (int r = 0; r < 4; ++r) {
        long long row = m0 + wm + mt * 16 + lq * 4 + r;
        long long col = n0 + wn + nt * 16 + lr;
        float v = acc[mt][nt][r];
        if (Cf) Cf[row * N + col] = v;
        else C[row * N + col] = f2b(v);
      }
}

// ---------------- causal flash attention v2 ----------------
// Q-tile 128 (32 q/wave, 2 m-tiles), K-tile 64. S^T = K*Q^T so softmax rows
// live along lanes (2 shuffles/reduce) and P writes are packed b64.
// K/V staged via global_load_lds into XOR-swizzled LDS. qt reversed for balance.
__global__ __launch_bounds__(256, 3) void attn_k(
    const u16* __restrict__ Q, const u16* __restrict__ K,
    const u16* __restrict__ Vt, u16* __restrict__ Y) {
  __shared__ u16 Ks[64 * 128];        // row=key, 16 chunks/row, slot=(g+key)&15
  __shared__ u16 Vs[128 * 64];        // row=d, 8 chunks/row, slot=(g+d)&7
  __shared__ u16 Ps[4][32 * 72];      // per-wave P [q][key], pad 64->72
  int qt = gridDim.x - 1 - blockIdx.x;     // heavy blocks first
  int bh = blockIdx.y;
  int b = bh >> 4, h = bh & 15;
  int tid = threadIdx.x, lane = tid & 63, wave = tid >> 6;
  int lr = lane & 15, lq = lane >> 4;
  int qbase = qt * 128 + wave * 32;

  // Q fragments as B-operand: B[k=d][n=q], lane n=lr, k=lq*8+j
  bf16x8 aq[2][4];
#pragma unroll
  for (int n2 = 0; n2 < 2; ++n2) {
    const u16* qp = Q + (((long long)b * T_SEQ + qbase + n2 * 16 + lr) * NHEAD + h) * HDIM;
#pragma unroll
    for (int kt = 0; kt < 4; ++kt)
      aq[n2][kt] = *reinterpret_cast<const bf16x8*>(qp + kt * 32 + lq * 8);
  }

  // staging pointers (4 chunks each for K and V per thread)
  const u16* kp[4];
  const u16* vp[4];
#pragma unroll
  for (int p = 0; p < 4; ++p) {
    int c = p * 256 + wave * 64 + lane;
    int key = c >> 4, sk = c & 15, gk = (sk - key) & 15;
    kp[p] = K + (((long long)b * T_SEQ + key) * NHEAD + h) * HDIM + gk * 8;
    int d = c >> 3, sv = c & 7, gv = (sv - d) & 7;
    vp[p] = Vt + ((long long)bh * HDIM + d) * T_SEQ + gv * 8;
  }

  float m_s[2], l_s[2];
#pragma unroll
  for (int n2 = 0; n2 < 2; ++n2) { m_s[n2] = -INFINITY; l_s[n2] = 0.f; }
  f32x4 o[2][8] = {};

  int niter = 2 * qt + 2;
  for (int j = 0; j < niter; ++j) {
    __syncthreads();
#pragma unroll
    for (int p = 0; p < 4; ++p) {
      __builtin_amdgcn_global_load_lds(
          (g_u32*)(kp[p] + (long long)j * 64 * NHEAD * HDIM),
          (l_u32*)(Ks + p * 2048 + wave * 512), 16, 0, 0);
      __builtin_amdgcn_global_load_lds(
          (g_u32*)(vp[p] + j * 64),
          (l_u32*)(Vs + p * 2048 + wave * 512), 16, 0, 0);
    }
    __syncthreads();

    // S^T tiles: m=key (4 tiles), n=q (2 tiles)
    f32x4 s[4][2];
#pragma unroll
    for (int mt = 0; mt < 4; ++mt) {
      int key = mt * 16 + lr;
      bf16x8 ak[4];
#pragma unroll
      for (int kt = 0; kt < 4; ++kt) {
        int slot = (kt * 4 + lq + key) & 15;
        ak[kt] = *reinterpret_cast<const bf16x8*>(&Ks[key * 128 + slot * 8]);
      }
#pragma unroll
      for (int n2 = 0; n2 < 2; ++n2) {
        f32x4 acc = {};
#pragma unroll
        for (int kt = 0; kt < 4; ++kt)
          acc = __builtin_amdgcn_mfma_f32_16x16x32_bf16(ak[kt], aq[n2][kt], acc, 0, 0, 0);
        s[mt][n2] = acc;
      }
    }

    // causal mask (only the last two tiles can cross the diagonal)
    if (j >= 2 * qt) {
#pragma unroll
      for (int mt = 0; mt < 4; ++mt)
#pragma unroll
        for (int n2 = 0; n2 < 2; ++n2) {
          int q = qbase + n2 * 16 + lr;
#pragma unroll
          for (int r = 0; r < 4; ++r) {
            int key = j * 64 + mt * 16 + lq * 4 + r;
            if (key > q) s[mt][n2][r] = -INFINITY;
          }
        }
    }

    // online softmax: lane holds 16 keys of q=(n2*16+lr)
    float alpha[2];
#pragma unroll
    for (int n2 = 0; n2 < 2; ++n2) {
      float mx = s[0][n2][0];
#pragma unroll
      for (int mt = 0; mt < 4; ++mt)
#pragma unroll
        for (int r = 0; r < 4; ++r) mx = fmaxf(mx, s[mt][n2][r]);
      mx = fmaxf(mx, __shfl_xor(mx, 16, 64));
      mx = fmaxf(mx, __shfl_xor(mx, 32, 64));
      float mn = fmaxf(m_s[n2], mx);
      alpha[n2] = __expf(m_s[n2] - mn);
      m_s[n2] = mn;
      float sum = 0.f;
      int q = n2 * 16 + lr;
#pragma unroll
      for (int mt = 0; mt < 4; ++mt) {
        ushort4 pk;
        float p0 = __expf(s[mt][n2][0] - mn);
        float p1 = __expf(s[mt][n2][1] - mn);
        float p2 = __expf(s[mt][n2][2] - mn);
        float p3 = __expf(s[mt][n2][3] - mn);
        sum += (p0 + p1) + (p2 + p3);
        pk.x = f2b(p0); pk.y = f2b(p1); pk.z = f2b(p2); pk.w = f2b(p3);
        *reinterpret_cast<ushort4*>(&Ps[wave][q * 72 + mt * 16 + lq * 4]) = pk;
      }
      sum += __shfl_xor(sum, 16, 64);
      sum += __shfl_xor(sum, 32, 64);
      l_s[n2] = l_s[n2] * alpha[n2] + sum;
    }

    // rescale O (alpha broadcast: q of O-lane = q2*16 + lq*4 + r)
#pragma unroll
    for (int q2 = 0; q2 < 2; ++q2)
#pragma unroll
      for (int r = 0; r < 4; ++r) {
        float a_o = __shfl(alpha[q2], lq * 4 + r, 16);
#pragma unroll
        for (int dt = 0; dt < 8; ++dt) o[q2][dt][r] *= a_o;
      }

    // PV: A = P[q][key] from Ps (same-wave DS in-order, no barrier needed)
#pragma unroll
    for (int kh = 0; kh < 2; ++kh) {
      bf16x8 ap[2];
#pragma unroll
      for (int q2 = 0; q2 < 2; ++q2)
        ap[q2] = *reinterpret_cast<const bf16x8*>(
            &Ps[wave][(q2 * 16 + lr) * 72 + kh * 32 + lq * 8]);
#pragma unroll
      for (int dt = 0; dt < 8; ++dt) {
        int d = dt * 16 + lr;
        int slot = (kh * 4 + lq + d) & 7;
        bf16x8 bv = *reinterpret_cast<const bf16x8*>(&Vs[d * 64 + slot * 8]);
#pragma unroll
        for (int q2 = 0; q2 < 2; ++q2)
          o[q2][dt] = __builtin_amdgcn_mfma_f32_16x16x32_bf16(ap[q2], bv, o[q2][dt], 0, 0, 0);
      }
    }
  }

  // epilogue
#pragma unroll
  for (int q2 = 0; q2 < 2; ++q2)
#pragma unroll
    for (int r = 0; r < 4; ++r) {
      float li = __shfl(l_s[q2], lq * 4 + r, 16);
      float inv = 1.0f / li;
      int q = qbase + q2 * 16 + lq * 4 + r;
      u16* yp = Y + (((long long)b * T_SEQ + q) * NHEAD + h) * HDIM;
#pragma unroll
      for (int dt = 0; dt < 8; ++dt)
        yp[dt * 16 + lr] = f2b(o[q2][dt][r] * inv);
    }
}

extern "C" void kernel_launch(void* const* d_in, const int* in_sizes, int n_in,
                              void* d_out, int out_size, void* d_ws, size_t ws_size,
                              hipStream_t stream) {
  (void)in_sizes; (void)n_in; (void)out_size; (void)ws_size;
  const float* x  = (const float*)d_in[0];
  const float* wq = (const float*)d_in[1];
  const float* wk = (const float*)d_in[2];
  const float* wv = (const float*)d_in[3];
  const float* wo = (const float*)d_in[4];
  float* out = (float*)d_out;

  char* ws = (char*)d_ws;
  size_t off = 0;
  auto alloc = [&](size_t bytes) {
    char* p = ws + off;
    off += (bytes + 255) & ~(size_t)255;
    return p;
  };
  const size_t NTOK = (size_t)BATCH * T_SEQ;
  const size_t XE = NTOK * E_DIM;
  const size_t WE = (size_t)E_DIM * E_DIM;

  u16* xb  = (u16*)alloc(XE * 2);
  u16* wqt = (u16*)alloc(WE * 2);
  u16* wkt = (u16*)alloc(WE * 2);
  u16* wvt = (u16*)alloc(WE * 2);
  u16* wot = (u16*)alloc(WE * 2);
  u16* Qb  = (u16*)alloc(XE * 2);
  u16* Kb  = (u16*)alloc(XE * 2);
  u16* Vb  = (u16*)alloc(XE * 2);
  u16* Vt  = (u16*)alloc(XE * 2);
  u16* Yb  = (u16*)alloc(XE * 2);
  float* cost = (float*)alloc((size_t)T_SEQ * 64 * 4);
  float* sint = (float*)alloc((size_t)T_SEQ * 64 * 4);

  convert_f32_bf16<<<XE / 1024, 256, 0, stream>>>(x, xb, (int)XE);
  dim3 gw(E_DIM / 64, E_DIM / 64);
  convt_w_k<<<gw, 256, 0, stream>>>(wq, wqt);
  convt_w_k<<<gw, 256, 0, stream>>>(wk, wkt);
  convt_w_k<<<gw, 256, 0, stream>>>(wv, wvt);
  convt_w_k<<<gw, 256, 0, stream>>>(wo, wot);
  rope_tables_k<<<(T_SEQ * 64) / 256, 256, 0, stream>>>(cost, sint);

  dim3 gq(E_DIM / 128, NTOK / 128, 3);
  gemm_bt_k<<<gq, 256, 0, stream>>>(xb, wqt, wkt, wvt, Qb, Kb, Vb, nullptr,
                                    (int)NTOK, E_DIM, E_DIM);

  rope_rms_k<<<(unsigned)(NTOK * NHEAD / 4), 256, 0, stream>>>(Qb, cost, sint, 0.08838834764831845f);
  rope_rms_k<<<(unsigned)(NTOK * NHEAD / 4), 256, 0, stream>>>(Kb, cost, sint, 1.0f);

  dim3 gt(T_SEQ / 64, HDIM / 64, BATCH * NHEAD);
  transpose_v_k<<<gt, 256, 0, stream>>>(Vb, Vt);

  dim3 ga(T_SEQ / 128, BATCH * NHEAD);
  attn_k<<<ga, 256, 0, stream>>>(Qb, Kb, Vt, Yb);

  dim3 go(E_DIM / 128, NTOK / 128, 1);
  gemm_bt_k<<<go, 256, 0, stream>>>(Yb, wot, wot, wot, nullptr, nullptr, nullptr, out,
                                    (int)NTOK, E_DIM, E_DIM);
}

// Round 4
// 791.616 us; speedup vs baseline: 2.3753x; 1.1531x over previous
//
#include <hip/hip_runtime.h>
#include <math.h>

#define T_SEQ 2048
#define BATCH 4
#define E_DIM 2048
#define NHEAD 16
#define HDIM 128
#define RMS_EPS 1.1920929e-07f
#define NQT (T_SEQ / 128)          // 16 q-tiles of 128

typedef unsigned short u16;
typedef __attribute__((ext_vector_type(8))) unsigned short u16x8;
typedef __attribute__((ext_vector_type(8))) short bf16x8;
typedef __attribute__((ext_vector_type(4))) float f32x4;

typedef const __attribute__((address_space(1))) unsigned int g_u32;
typedef __attribute__((address_space(3))) unsigned int l_u32;

static __device__ __forceinline__ u16 f2b(float f) {
  unsigned int u = __builtin_bit_cast(unsigned int, f);
  u += 0x7fffu + ((u >> 16) & 1u);
  return (u16)(u >> 16);
}
static __device__ __forceinline__ float b2f(u16 v) {
  return __builtin_bit_cast(float, ((unsigned int)v) << 16);
}

// ---------------- fp32 -> bf16 convert (x only) ----------------
__global__ __launch_bounds__(256) void convert_f32_bf16(
    const float* __restrict__ src, u16* __restrict__ dst, int n) {
  int i = (blockIdx.x * 256 + threadIdx.x) * 4;
  if (i >= n) return;
  float4 v = *reinterpret_cast<const float4*>(src + i);
  ushort4 o;
  o.x = f2b(v.x); o.y = f2b(v.y); o.z = f2b(v.z); o.w = f2b(v.w);
  *reinterpret_cast<ushort4*>(dst + i) = o;
}

// ---------------- fused fp32->bf16 convert + transpose: Wt[n][k]=W[k][n] ----
__global__ __launch_bounds__(256) void convt_w_k(
    const float* __restrict__ W, u16* __restrict__ Wt) {
  __shared__ u16 tile[64][72];
  int c0 = blockIdx.x * 64;
  int r0 = blockIdx.y * 64;
  int tid = threadIdx.x;
  int lrow = tid >> 2;
  int lcol = (tid & 3) * 16;
#pragma unroll
  for (int i = 0; i < 4; ++i) {
    float4 v = *reinterpret_cast<const float4*>(
        W + (long long)(r0 + lrow) * E_DIM + c0 + lcol + i * 4);
    tile[lrow][lcol + i * 4 + 0] = f2b(v.x);
    tile[lrow][lcol + i * 4 + 1] = f2b(v.y);
    tile[lrow][lcol + i * 4 + 2] = f2b(v.z);
    tile[lrow][lcol + i * 4 + 3] = f2b(v.w);
  }
  __syncthreads();
  int wrow = tid >> 2;
  int wcol = (tid & 3) * 16;
  u16 o[16];
#pragma unroll
  for (int i = 0; i < 16; ++i) o[i] = tile[wcol + i][wrow];
  u16* dst = Wt + (long long)(c0 + wrow) * E_DIM + r0 + wcol;
  *reinterpret_cast<u16x8*>(dst)     = *reinterpret_cast<u16x8*>(&o[0]);
  *reinterpret_cast<u16x8*>(dst + 8) = *reinterpret_cast<u16x8*>(&o[8]);
}

// ---------------- rope tables (double precision trig) ----------------
__global__ __launch_bounds__(256) void rope_tables_k(
    float* __restrict__ cost, float* __restrict__ sint) {
  int idx = blockIdx.x * 256 + threadIdx.x;
  int i = idx & 63, t = idx >> 6;
  double inv = pow(10000.0, -(double)i / 64.0);
  double ang = (double)t * inv;
  cost[idx] = (float)cos(ang);
  sint[idx] = (float)sin(ang);
}

// ---------------- fused rope + rmsnorm (in-place on bf16 Q and K) ----------
__global__ __launch_bounds__(256) void rope_rms_k(
    u16* __restrict__ Qb, u16* __restrict__ Kb, const float* __restrict__ cost,
    const float* __restrict__ sint) {
  int half = gridDim.x >> 1;
  int isK = blockIdx.x >= half;
  u16* qk = isK ? Kb : Qb;
  float outscale = isK ? 1.0f : 0.08838834764831845f;  // fold 1/sqrt(128) into Q
  int wave = threadIdx.x >> 6;
  int lane = threadIdx.x & 63;
  long long row = (long long)(blockIdx.x - (isK ? half : 0)) * 4 + wave;
  int th = (int)(row >> 4);
  int t = th & (T_SEQ - 1);
  u16* p = qk + row * HDIM;
  float x1 = b2f(p[lane]);
  float x2 = b2f(p[lane + 64]);
  float c = cost[t * 64 + lane];
  float s = sint[t * 64 + lane];
  float o1 = x1 * c - x2 * s;
  float o2 = x1 * s + x2 * c;
  float ss = o1 * o1 + o2 * o2;
#pragma unroll
  for (int m = 32; m >= 1; m >>= 1) ss += __shfl_xor(ss, m, 64);
  float r = rsqrtf(ss * (1.0f / 128.0f) + RMS_EPS) * outscale;
  p[lane] = f2b(o1 * r);
  p[lane + 64] = f2b(o2 * r);
}

// ---------------- V transpose: [B,T,H,D] -> per (b,h): [D][T] ----------------
__global__ __launch_bounds__(256) void transpose_v_k(
    const u16* __restrict__ V, u16* __restrict__ Vt) {
  __shared__ u16 tile[64][72];
  int t0 = blockIdx.x * 64, d0 = blockIdx.y * 64;
  int bh = blockIdx.z;
  int b = bh >> 4, h = bh & 15;
  int tid = threadIdx.x;
  int lrow = tid >> 3;
  int lcol = (tid & 7) * 8;
#pragma unroll
  for (int pass = 0; pass < 2; ++pass) {
    int row = lrow + pass * 32;
    const u16* src = V + ((((long long)b * T_SEQ + t0 + row) * NHEAD + h) << 7) + d0 + lcol;
    *reinterpret_cast<u16x8*>(&tile[row][lcol]) = *reinterpret_cast<const u16x8*>(src);
  }
  __syncthreads();
#pragma unroll
  for (int pass = 0; pass < 2; ++pass) {
    int drow = (tid >> 3) + pass * 32;
    int tcol = (tid & 7) * 8;
    u16x8 o;
#pragma unroll
    for (int i = 0; i < 8; ++i) o[i] = tile[tcol + i][drow];
    u16* dst = Vt + ((long long)bh * HDIM + d0 + drow) * T_SEQ + t0 + tcol;
    *reinterpret_cast<u16x8*>(dst) = o;
  }
}

// ---------------- bf16 MFMA GEMM (m97 structure) ----------------
__global__ __launch_bounds__(256) void gemm_bt_k(
    const u16* __restrict__ A,
    const u16* __restrict__ Bt0, const u16* __restrict__ Bt1, const u16* __restrict__ Bt2,
    u16* __restrict__ C0, u16* __restrict__ C1, u16* __restrict__ C2,
    float* __restrict__ Cf, int M, int N, int K) {
  const u16* Bt = blockIdx.z == 0 ? Bt0 : (blockIdx.z == 1 ? Bt1 : Bt2);
  u16* C = blockIdx.z == 0 ? C0 : (blockIdx.z == 1 ? C1 : C2);
  __shared__ u16 As[128 * 32];
  __shared__ u16 Bs[128 * 32];
  int tid = threadIdx.x;
  int lane = tid & 63, wave = tid >> 6;
  int wm = (wave >> 1) * 64, wn = (wave & 1) * 64;
  int m0 = blockIdx.y * 128, n0 = blockIdx.x * 128;
  int lr = lane & 15, lq = lane >> 4;
  f32x4 acc[4][4] = {};
  int srow = tid >> 2;
  int sslot = tid & 3;

  for (int kk = 0; kk < K; kk += 32) {
    __syncthreads();
#pragma unroll
    for (int p = 0; p < 2; ++p) {
      int row = srow + p * 64;
      int kg = (sslot - (row >> 1)) & 3;
      __builtin_amdgcn_global_load_lds(
          (g_u32*)(A + (long long)(m0 + row) * K + kk + kg * 8),
          (l_u32*)(As + p * 2048 + wave * 512), 16, 0, 0);
      __builtin_amdgcn_global_load_lds(
          (g_u32*)(Bt + (long long)(n0 + row) * K + kk + kg * 8),
          (l_u32*)(Bs + p * 2048 + wave * 512), 16, 0, 0);
    }
    __syncthreads();
    bf16x8 af[4], bfg[4];
#pragma unroll
    for (int mt = 0; mt < 4; ++mt) {
      int r = wm + mt * 16 + lr;
      int s = (lq + (r >> 1)) & 3;
      af[mt] = *reinterpret_cast<const bf16x8*>(&As[r * 32 + s * 8]);
    }
#pragma unroll
    for (int nt = 0; nt < 4; ++nt) {
      int r = wn + nt * 16 + lr;
      int s = (lq + (r >> 1)) & 3;
      bfg[nt] = *reinterpret_cast<const bf16x8*>(&Bs[r * 32 + s * 8]);
    }
#pragma unroll
    for (int mt = 0; mt < 4; ++mt)
#pragma unroll
      for (int nt = 0; nt < 4; ++nt)
        acc[mt][nt] = __builtin_amdgcn_mfma_f32_16x16x32_bf16(af[mt], bfg[nt], acc[mt][nt], 0, 0, 0);
  }
#pragma unroll
  for (int mt = 0; mt < 4; ++mt)
#pragma unroll
    for (int nt = 0; nt < 4; ++nt)
#pragma unroll
      for (int r = 0; r < 4; ++r) {
        long long row = m0 + wm + mt * 16 + lq * 4 + r;
        long long col = n0 + wn + nt * 16 + lr;
        float v = acc[mt][nt][r];
        if (Cf) Cf[row * N + col] = v;
        else C[row * N + col] = f2b(v);
      }
}

// ---------------- causal flash attention v3 ----------------
// Work-balanced: block (pair, bh) runs q-tile (NQT-1-pair) then (pair):
// every block = exactly 2*NQT+2 iterations -> no causal tail, 2 blocks/CU.
// S^T = K*Q^T (softmax rows along lanes); alpha/l broadcast via per-wave LDS
// instead of shuffles.
__global__ __launch_bounds__(256, 3) void attn_k(
    const u16* __restrict__ Q, const u16* __restrict__ K,
    const u16* __restrict__ Vt, u16* __restrict__ Y) {
  __shared__ u16 Ks[64 * 128];        // row=key, 16 chunks/row, slot=(g+key)&15
  __shared__ u16 Vs[128 * 64];        // row=d, 8 chunks/row, slot=(g+d)&7
  __shared__ u16 Ps[4][32 * 72];      // per-wave P [q][key], pad 64->72
  __shared__ float Al[4][32];         // per-wave alpha / l broadcast
  int pair = blockIdx.x;              // 0..NQT/2-1
  int bh = blockIdx.y;
  int b = bh >> 4, h = bh & 15;
  int tid = threadIdx.x, lane = tid & 63, wave = tid >> 6;
  int lr = lane & 15, lq = lane >> 4;

  // staging pointers (qt-independent; 4 chunks each for K and V per thread)
  const u16* kp[4];
  const u16* vp[4];
#pragma unroll
  for (int p = 0; p < 4; ++p) {
    int c = p * 256 + wave * 64 + lane;
    int key = c >> 4, sk = c & 15, gk = (sk - key) & 15;
    kp[p] = K + (((long long)b * T_SEQ + key) * NHEAD + h) * HDIM + gk * 8;
    int d = c >> 3, sv = c & 7, gv = (sv - d) & 7;
    vp[p] = Vt + ((long long)bh * HDIM + d) * T_SEQ + gv * 8;
  }

#pragma unroll 1
  for (int phase = 0; phase < 2; ++phase) {
    int qt = phase == 0 ? (NQT - 1 - pair) : pair;
    int qbase = qt * 128 + wave * 32;

    // Q fragments as B-operand: B[k=d][n=q], lane n=lr, k=lq*8+j
    bf16x8 aq[2][4];
#pragma unroll
    for (int n2 = 0; n2 < 2; ++n2) {
      const u16* qp = Q + (((long long)b * T_SEQ + qbase + n2 * 16 + lr) * NHEAD + h) * HDIM;
#pragma unroll
      for (int kt = 0; kt < 4; ++kt)
        aq[n2][kt] = *reinterpret_cast<const bf16x8*>(qp + kt * 32 + lq * 8);
    }

    float m_s[2], l_s[2];
#pragma unroll
    for (int n2 = 0; n2 < 2; ++n2) { m_s[n2] = -INFINITY; l_s[n2] = 0.f; }
    f32x4 o[2][8] = {};

    int niter = 2 * qt + 2;
    for (int j = 0; j < niter; ++j) {
      __syncthreads();
#pragma unroll
      for (int p = 0; p < 4; ++p) {
        __builtin_amdgcn_global_load_lds(
            (g_u32*)(kp[p] + (long long)j * 64 * NHEAD * HDIM),
            (l_u32*)(Ks + p * 2048 + wave * 512), 16, 0, 0);
        __builtin_amdgcn_global_load_lds(
            (g_u32*)(vp[p] + j * 64),
            (l_u32*)(Vs + p * 2048 + wave * 512), 16, 0, 0);
      }
      __syncthreads();

      // S^T tiles: m=key (4 tiles), n=q (2 tiles)
      f32x4 s[4][2];
#pragma unroll
      for (int mt = 0; mt < 4; ++mt) {
        int key = mt * 16 + lr;
        bf16x8 ak[4];
#pragma unroll
        for (int kt = 0; kt < 4; ++kt) {
          int slot = (kt * 4 + lq + key) & 15;
          ak[kt] = *reinterpret_cast<const bf16x8*>(&Ks[key * 128 + slot * 8]);
        }
#pragma unroll
        for (int n2 = 0; n2 < 2; ++n2) {
          f32x4 acc = {};
#pragma unroll
          for (int kt = 0; kt < 4; ++kt)
            acc = __builtin_amdgcn_mfma_f32_16x16x32_bf16(ak[kt], aq[n2][kt], acc, 0, 0, 0);
          s[mt][n2] = acc;
        }
      }

      // causal mask (only the last two tiles can cross the diagonal)
      if (j >= 2 * qt) {
#pragma unroll
        for (int mt = 0; mt < 4; ++mt)
#pragma unroll
          for (int n2 = 0; n2 < 2; ++n2) {
            int q = qbase + n2 * 16 + lr;
#pragma unroll
            for (int r = 0; r < 4; ++r) {
              int key = j * 64 + mt * 16 + lq * 4 + r;
              if (key > q) s[mt][n2][r] = -INFINITY;
            }
          }
      }

      // online softmax: lane holds 16 keys of q=(n2*16+lr)
      float alpha[2];
#pragma unroll
      for (int n2 = 0; n2 < 2; ++n2) {
        float mx = s[0][n2][0];
#pragma unroll
        for (int mt = 0; mt < 4; ++mt)
#pragma unroll
          for (int r = 0; r < 4; ++r) mx = fmaxf(mx, s[mt][n2][r]);
        mx = fmaxf(mx, __shfl_xor(mx, 16, 64));
        mx = fmaxf(mx, __shfl_xor(mx, 32, 64));
        float mn = fmaxf(m_s[n2], mx);
        alpha[n2] = __expf(m_s[n2] - mn);
        m_s[n2] = mn;
        float sum = 0.f;
        int q = n2 * 16 + lr;
#pragma unroll
        for (int mt = 0; mt < 4; ++mt) {
          ushort4 pk;
          float p0 = __expf(s[mt][n2][0] - mn);
          float p1 = __expf(s[mt][n2][1] - mn);
          float p2 = __expf(s[mt][n2][2] - mn);
          float p3 = __expf(s[mt][n2][3] - mn);
          sum += (p0 + p1) + (p2 + p3);
          pk.x = f2b(p0); pk.y = f2b(p1); pk.z = f2b(p2); pk.w = f2b(p3);
          *reinterpret_cast<ushort4*>(&Ps[wave][q * 72 + mt * 16 + lq * 4]) = pk;
        }
        sum += __shfl_xor(sum, 16, 64);
        sum += __shfl_xor(sum, 32, 64);
        l_s[n2] = l_s[n2] * alpha[n2] + sum;
      }

      // broadcast alpha to O-layout lanes via per-wave LDS (in-order DS)
      if (lq == 0) {
        Al[wave][lr] = alpha[0];
        Al[wave][16 + lr] = alpha[1];
      }
#pragma unroll
      for (int q2 = 0; q2 < 2; ++q2) {
        f32x4 av = *reinterpret_cast<const f32x4*>(&Al[wave][q2 * 16 + lq * 4]);
#pragma unroll
        for (int r = 0; r < 4; ++r)
#pragma unroll
          for (int dt = 0; dt < 8; ++dt) o[q2][dt][r] *= av[r];
      }

      // PV: A = P[q][key] from Ps (same-wave DS in-order, no barrier needed)
#pragma unroll
      for (int kh = 0; kh < 2; ++kh) {
        bf16x8 ap[2];
#pragma unroll
        for (int q2 = 0; q2 < 2; ++q2)
          ap[q2] = *reinterpret_cast<const bf16x8*>(
              &Ps[wave][(q2 * 16 + lr) * 72 + kh * 32 + lq * 8]);
#pragma unroll
        for (int dt = 0; dt < 8; ++dt) {
          int d = dt * 16 + lr;
          int slot = (kh * 4 + lq + d) & 7;
          bf16x8 bv = *reinterpret_cast<const bf16x8*>(&Vs[d * 64 + slot * 8]);
#pragma unroll
          for (int q2 = 0; q2 < 2; ++q2)
            o[q2][dt] = __builtin_amdgcn_mfma_f32_16x16x32_bf16(ap[q2], bv, o[q2][dt], 0, 0, 0);
        }
      }
    }

    // epilogue: l broadcast via LDS, then store
    if (lq == 0) {
      Al[wave][lr] = l_s[0];
      Al[wave][16 + lr] = l_s[1];
    }
#pragma unroll
    for (int q2 = 0; q2 < 2; ++q2) {
      f32x4 lv = *reinterpret_cast<const f32x4*>(&Al[wave][q2 * 16 + lq * 4]);
#pragma unroll
      for (int r = 0; r < 4; ++r) {
        float inv = 1.0f / lv[r];
        int q = qbase + q2 * 16 + lq * 4 + r;
        u16* yp = Y + (((long long)b * T_SEQ + q) * NHEAD + h) * HDIM;
#pragma unroll
        for (int dt = 0; dt < 8; ++dt)
          yp[dt * 16 + lr] = f2b(o[q2][dt][r] * inv);
      }
    }
  }
}

extern "C" void kernel_launch(void* const* d_in, const int* in_sizes, int n_in,
                              void* d_out, int out_size, void* d_ws, size_t ws_size,
                              hipStream_t stream) {
  (void)in_sizes; (void)n_in; (void)out_size; (void)ws_size;
  const float* x  = (const float*)d_in[0];
  const float* wq = (const float*)d_in[1];
  const float* wk = (const float*)d_in[2];
  const float* wv = (const float*)d_in[3];
  const float* wo = (const float*)d_in[4];
  float* out = (float*)d_out;

  char* ws = (char*)d_ws;
  size_t off = 0;
  auto alloc = [&](size_t bytes) {
    char* p = ws + off;
    off += (bytes + 255) & ~(size_t)255;
    return p;
  };
  const size_t NTOK = (size_t)BATCH * T_SEQ;
  const size_t XE = NTOK * E_DIM;
  const size_t WE = (size_t)E_DIM * E_DIM;

  u16* xb  = (u16*)alloc(XE * 2);
  u16* wqt = (u16*)alloc(WE * 2);
  u16* wkt = (u16*)alloc(WE * 2);
  u16* wvt = (u16*)alloc(WE * 2);
  u16* wot = (u16*)alloc(WE * 2);
  u16* Qb  = (u16*)alloc(XE * 2);
  u16* Kb  = (u16*)alloc(XE * 2);
  u16* Vb  = (u16*)alloc(XE * 2);
  u16* Vt  = (u16*)alloc(XE * 2);
  u16* Yb  = (u16*)alloc(XE * 2);
  float* cost = (float*)alloc((size_t)T_SEQ * 64 * 4);
  float* sint = (float*)alloc((size_t)T_SEQ * 64 * 4);

  convert_f32_bf16<<<XE / 1024, 256, 0, stream>>>(x, xb, (int)XE);
  dim3 gw(E_DIM / 64, E_DIM / 64);
  convt_w_k<<<gw, 256, 0, stream>>>(wq, wqt);
  convt_w_k<<<gw, 256, 0, stream>>>(wk, wkt);
  convt_w_k<<<gw, 256, 0, stream>>>(wv, wvt);
  convt_w_k<<<gw, 256, 0, stream>>>(wo, wot);
  rope_tables_k<<<(T_SEQ * 64) / 256, 256, 0, stream>>>(cost, sint);

  dim3 gq(E_DIM / 128, NTOK / 128, 3);
  gemm_bt_k<<<gq, 256, 0, stream>>>(xb, wqt, wkt, wvt, Qb, Kb, Vb, nullptr,
                                    (int)NTOK, E_DIM, E_DIM);

  // fused rope+rms for Q and K in one dispatch
  rope_rms_k<<<(unsigned)(NTOK * NHEAD / 4) * 2, 256, 0, stream>>>(Qb, Kb, cost, sint);

  dim3 gt(T_SEQ / 64, HDIM / 64, BATCH * NHEAD);
  transpose_v_k<<<gt, 256, 0, stream>>>(Vb, Vt);

  dim3 ga(NQT / 2, BATCH * NHEAD);
  attn_k<<<ga, 256, 0, stream>>>(Qb, Kb, Vt, Yb);

  dim3 go(E_DIM / 128, NTOK / 128, 1);
  gemm_bt_k<<<go, 256, 0, stream>>>(Yb, wot, wot, wot, nullptr, nullptr, nullptr, out,
                                    (int)NTOK, E_DIM, E_DIM);
}

// Round 5
// 729.098 us; speedup vs baseline: 2.5790x; 1.0857x over previous
//
#include <hip/hip_runtime.h>
#include <math.h>

#define T_SEQ 2048
#define BATCH 4
#define E_DIM 2048
#define NHEAD 16
#define HDIM 128
#define RMS_EPS 1.1920929e-07f
#define NQT (T_SEQ / 128)          // 16 q-tiles of 128

typedef unsigned short u16;
typedef __attribute__((ext_vector_type(8))) unsigned short u16x8;
typedef __attribute__((ext_vector_type(8))) short bf16x8;
typedef __attribute__((ext_vector_type(4))) float f32x4;
typedef __attribute__((ext_vector_type(16))) float f32x16;

typedef const __attribute__((address_space(1))) unsigned int g_u32;
typedef __attribute__((address_space(3))) unsigned int l_u32;

static __device__ __forceinline__ u16 f2b(float f) {
  unsigned int u = __builtin_bit_cast(unsigned int, f);
  u += 0x7fffu + ((u >> 16) & 1u);
  return (u16)(u >> 16);
}
static __device__ __forceinline__ float b2f(u16 v) {
  return __builtin_bit_cast(float, ((unsigned int)v) << 16);
}

// ---------------- fp32 -> bf16 convert (x only) ----------------
__global__ __launch_bounds__(256) void convert_f32_bf16(
    const float* __restrict__ src, u16* __restrict__ dst, int n) {
  int i = (blockIdx.x * 256 + threadIdx.x) * 4;
  if (i >= n) return;
  float4 v = *reinterpret_cast<const float4*>(src + i);
  ushort4 o;
  o.x = f2b(v.x); o.y = f2b(v.y); o.z = f2b(v.z); o.w = f2b(v.w);
  *reinterpret_cast<ushort4*>(dst + i) = o;
}

// ---------------- fused fp32->bf16 convert + transpose: Wt[n][k]=W[k][n] ----
__global__ __launch_bounds__(256) void convt_w_k(
    const float* __restrict__ W, u16* __restrict__ Wt) {
  __shared__ u16 tile[64][72];
  int c0 = blockIdx.x * 64;
  int r0 = blockIdx.y * 64;
  int tid = threadIdx.x;
  int lrow = tid >> 2;
  int lcol = (tid & 3) * 16;
#pragma unroll
  for (int i = 0; i < 4; ++i) {
    float4 v = *reinterpret_cast<const float4*>(
        W + (long long)(r0 + lrow) * E_DIM + c0 + lcol + i * 4);
    tile[lrow][lcol + i * 4 + 0] = f2b(v.x);
    tile[lrow][lcol + i * 4 + 1] = f2b(v.y);
    tile[lrow][lcol + i * 4 + 2] = f2b(v.z);
    tile[lrow][lcol + i * 4 + 3] = f2b(v.w);
  }
  __syncthreads();
  int wrow = tid >> 2;
  int wcol = (tid & 3) * 16;
  u16 o[16];
#pragma unroll
  for (int i = 0; i < 16; ++i) o[i] = tile[wcol + i][wrow];
  u16* dst = Wt + (long long)(c0 + wrow) * E_DIM + r0 + wcol;
  *reinterpret_cast<u16x8*>(dst)     = *reinterpret_cast<u16x8*>(&o[0]);
  *reinterpret_cast<u16x8*>(dst + 8) = *reinterpret_cast<u16x8*>(&o[8]);
}

// ---------------- rope tables (double precision trig) ----------------
__global__ __launch_bounds__(256) void rope_tables_k(
    float* __restrict__ cost, float* __restrict__ sint) {
  int idx = blockIdx.x * 256 + threadIdx.x;
  int i = idx & 63, t = idx >> 6;
  double inv = pow(10000.0, -(double)i / 64.0);
  double ang = (double)t * inv;
  cost[idx] = (float)cos(ang);
  sint[idx] = (float)sin(ang);
}

// ---------------- fused rope + rmsnorm (in-place on bf16 Q and K) ----------
__global__ __launch_bounds__(256) void rope_rms_k(
    u16* __restrict__ Qb, u16* __restrict__ Kb, const float* __restrict__ cost,
    const float* __restrict__ sint) {
  int half = gridDim.x >> 1;
  int isK = blockIdx.x >= half;
  u16* qk = isK ? Kb : Qb;
  float outscale = isK ? 1.0f : 0.08838834764831845f;  // fold 1/sqrt(128) into Q
  int wave = threadIdx.x >> 6;
  int lane = threadIdx.x & 63;
  long long row = (long long)(blockIdx.x - (isK ? half : 0)) * 4 + wave;
  int th = (int)(row >> 4);
  int t = th & (T_SEQ - 1);
  u16* p = qk + row * HDIM;
  float x1 = b2f(p[lane]);
  float x2 = b2f(p[lane + 64]);
  float c = cost[t * 64 + lane];
  float s = sint[t * 64 + lane];
  float o1 = x1 * c - x2 * s;
  float o2 = x1 * s + x2 * c;
  float ss = o1 * o1 + o2 * o2;
#pragma unroll
  for (int m = 32; m >= 1; m >>= 1) ss += __shfl_xor(ss, m, 64);
  float r = rsqrtf(ss * (1.0f / 128.0f) + RMS_EPS) * outscale;
  p[lane] = f2b(o1 * r);
  p[lane + 64] = f2b(o2 * r);
}

// ---------------- V transpose: [B,T,H,D] -> per (b,h): [D][T] ----------------
__global__ __launch_bounds__(256) void transpose_v_k(
    const u16* __restrict__ V, u16* __restrict__ Vt) {
  __shared__ u16 tile[64][72];
  int t0 = blockIdx.x * 64, d0 = blockIdx.y * 64;
  int bh = blockIdx.z;
  int b = bh >> 4, h = bh & 15;
  int tid = threadIdx.x;
  int lrow = tid >> 3;
  int lcol = (tid & 7) * 8;
#pragma unroll
  for (int pass = 0; pass < 2; ++pass) {
    int row = lrow + pass * 32;
    const u16* src = V + ((((long long)b * T_SEQ + t0 + row) * NHEAD + h) << 7) + d0 + lcol;
    *reinterpret_cast<u16x8*>(&tile[row][lcol]) = *reinterpret_cast<const u16x8*>(src);
  }
  __syncthreads();
#pragma unroll
  for (int pass = 0; pass < 2; ++pass) {
    int drow = (tid >> 3) + pass * 32;
    int tcol = (tid & 7) * 8;
    u16x8 o;
#pragma unroll
    for (int i = 0; i < 8; ++i) o[i] = tile[tcol + i][drow];
    u16* dst = Vt + ((long long)bh * HDIM + d0 + drow) * T_SEQ + t0 + tcol;
    *reinterpret_cast<u16x8*>(dst) = o;
  }
}

// ---------------- bf16 MFMA GEMM: 32x32x16 MFMA, BK=64 -----------------
// C[M,N] = A[M,K] * Bt[N,K]^T. 128x128 tile, 4 waves 2x2, each wave 2x2
// tiles of 32x32. global_load_lds width=16 into 8-slot xor-rotated LDS.
__global__ __launch_bounds__(256) void gemm_bt_k(
    const u16* __restrict__ A,
    const u16* __restrict__ Bt0, const u16* __restrict__ Bt1, const u16* __restrict__ Bt2,
    u16* __restrict__ C0, u16* __restrict__ C1, u16* __restrict__ C2,
    float* __restrict__ Cf, int M, int N, int K) {
  const u16* Bt = blockIdx.z == 0 ? Bt0 : (blockIdx.z == 1 ? Bt1 : Bt2);
  u16* C = blockIdx.z == 0 ? C0 : (blockIdx.z == 1 ? C1 : C2);
  __shared__ u16 As[128 * 64];   // row-major [row][64], 8 chunks/row, slot=(g+row)&7
  __shared__ u16 Bs[128 * 64];
  int tid = threadIdx.x;
  int lane = tid & 63, wave = tid >> 6;
  int wm = (wave >> 1) * 64, wn = (wave & 1) * 64;
  int m0 = blockIdx.y * 128, n0 = blockIdx.x * 128;
  int l5 = lane & 31, lh = lane >> 5;   // row-in-tile, k-half
  f32x16 acc[2][2] = {};

  // staging: 4 chunks each for A and B per thread
  const u16* pa[4];
  const u16* pb[4];
#pragma unroll
  for (int p = 0; p < 4; ++p) {
    int c = p * 256 + wave * 64 + lane;
    int row = c >> 3, s = c & 7, g = (s - row) & 7;
    pa[p] = A + (long long)(m0 + row) * K + g * 8;
    pb[p] = Bt + (long long)(n0 + row) * K + g * 8;
  }

  for (int kk = 0; kk < K; kk += 64) {
    __syncthreads();
#pragma unroll
    for (int p = 0; p < 4; ++p) {
      __builtin_amdgcn_global_load_lds((g_u32*)(pa[p] + kk),
          (l_u32*)(As + p * 2048 + wave * 512), 16, 0, 0);
      __builtin_amdgcn_global_load_lds((g_u32*)(pb[p] + kk),
          (l_u32*)(Bs + p * 2048 + wave * 512), 16, 0, 0);
    }
    __syncthreads();
#pragma unroll
    for (int kq = 0; kq < 4; ++kq) {      // k-quarter of 16
      int g = kq * 2 + lh;                 // 16B chunk index within row
      bf16x8 af[2], bf[2];
#pragma unroll
      for (int mt = 0; mt < 2; ++mt) {
        int r = wm + mt * 32 + l5;
        af[mt] = *reinterpret_cast<const bf16x8*>(&As[r * 64 + ((g + r) & 7) * 8]);
      }
#pragma unroll
      for (int nt = 0; nt < 2; ++nt) {
        int r = wn + nt * 32 + l5;
        bf[nt] = *reinterpret_cast<const bf16x8*>(&Bs[r * 64 + ((g + r) & 7) * 8]);
      }
#pragma unroll
      for (int mt = 0; mt < 2; ++mt)
#pragma unroll
        for (int nt = 0; nt < 2; ++nt)
          acc[mt][nt] = __builtin_amdgcn_mfma_f32_32x32x16_bf16(af[mt], bf[nt], acc[mt][nt], 0, 0, 0);
    }
  }
  // epilogue: C col = lane&31, row = (reg&3) + 8*(reg>>2) + 4*(lane>>5)
#pragma unroll
  for (int mt = 0; mt < 2; ++mt)
#pragma unroll
    for (int nt = 0; nt < 2; ++nt) {
      long long col = n0 + wn + nt * 32 + l5;
#pragma unroll
      for (int reg = 0; reg < 16; ++reg) {
        long long row = m0 + wm + mt * 32 + (reg & 3) + 8 * (reg >> 2) + 4 * lh;
        float v = acc[mt][nt][reg];
        if (Cf) Cf[row * N + col] = v;
        else C[row * N + col] = f2b(v);
      }
    }
}

// ---------------- causal flash attention v3 (unchanged) ----------------
__global__ __launch_bounds__(256, 3) void attn_k(
    const u16* __restrict__ Q, const u16* __restrict__ K,
    const u16* __restrict__ Vt, u16* __restrict__ Y) {
  __shared__ u16 Ks[64 * 128];        // row=key, 16 chunks/row, slot=(g+key)&15
  __shared__ u16 Vs[128 * 64];        // row=d, 8 chunks/row, slot=(g+d)&7
  __shared__ u16 Ps[4][32 * 72];      // per-wave P [q][key], pad 64->72
  __shared__ float Al[4][32];         // per-wave alpha / l broadcast
  int pair = blockIdx.x;              // 0..NQT/2-1
  int bh = blockIdx.y;
  int b = bh >> 4, h = bh & 15;
  int tid = threadIdx.x, lane = tid & 63, wave = tid >> 6;
  int lr = lane & 15, lq = lane >> 4;

  const u16* kp[4];
  const u16* vp[4];
#pragma unroll
  for (int p = 0; p < 4; ++p) {
    int c = p * 256 + wave * 64 + lane;
    int key = c >> 4, sk = c & 15, gk = (sk - key) & 15;
    kp[p] = K + (((long long)b * T_SEQ + key) * NHEAD + h) * HDIM + gk * 8;
    int d = c >> 3, sv = c & 7, gv = (sv - d) & 7;
    vp[p] = Vt + ((long long)bh * HDIM + d) * T_SEQ + gv * 8;
  }

#pragma unroll 1
  for (int phase = 0; phase < 2; ++phase) {
    int qt = phase == 0 ? (NQT - 1 - pair) : pair;
    int qbase = qt * 128 + wave * 32;

    bf16x8 aq[2][4];
#pragma unroll
    for (int n2 = 0; n2 < 2; ++n2) {
      const u16* qp = Q + (((long long)b * T_SEQ + qbase + n2 * 16 + lr) * NHEAD + h) * HDIM;
#pragma unroll
      for (int kt = 0; kt < 4; ++kt)
        aq[n2][kt] = *reinterpret_cast<const bf16x8*>(qp + kt * 32 + lq * 8);
    }

    float m_s[2], l_s[2];
#pragma unroll
    for (int n2 = 0; n2 < 2; ++n2) { m_s[n2] = -INFINITY; l_s[n2] = 0.f; }
    f32x4 o[2][8] = {};

    int niter = 2 * qt + 2;
    for (int j = 0; j < niter; ++j) {
      __syncthreads();
#pragma unroll
      for (int p = 0; p < 4; ++p) {
        __builtin_amdgcn_global_load_lds(
            (g_u32*)(kp[p] + (long long)j * 64 * NHEAD * HDIM),
            (l_u32*)(Ks + p * 2048 + wave * 512), 16, 0, 0);
        __builtin_amdgcn_global_load_lds(
            (g_u32*)(vp[p] + j * 64),
            (l_u32*)(Vs + p * 2048 + wave * 512), 16, 0, 0);
      }
      __syncthreads();

      f32x4 s[4][2];
#pragma unroll
      for (int mt = 0; mt < 4; ++mt) {
        int key = mt * 16 + lr;
        bf16x8 ak[4];
#pragma unroll
        for (int kt = 0; kt < 4; ++kt) {
          int slot = (kt * 4 + lq + key) & 15;
          ak[kt] = *reinterpret_cast<const bf16x8*>(&Ks[key * 128 + slot * 8]);
        }
#pragma unroll
        for (int n2 = 0; n2 < 2; ++n2) {
          f32x4 acc = {};
#pragma unroll
          for (int kt = 0; kt < 4; ++kt)
            acc = __builtin_amdgcn_mfma_f32_16x16x32_bf16(ak[kt], aq[n2][kt], acc, 0, 0, 0);
          s[mt][n2] = acc;
        }
      }

      if (j >= 2 * qt) {
#pragma unroll
        for (int mt = 0; mt < 4; ++mt)
#pragma unroll
          for (int n2 = 0; n2 < 2; ++n2) {
            int q = qbase + n2 * 16 + lr;
#pragma unroll
            for (int r = 0; r < 4; ++r) {
              int key = j * 64 + mt * 16 + lq * 4 + r;
              if (key > q) s[mt][n2][r] = -INFINITY;
            }
          }
      }

      float alpha[2];
#pragma unroll
      for (int n2 = 0; n2 < 2; ++n2) {
        float mx = s[0][n2][0];
#pragma unroll
        for (int mt = 0; mt < 4; ++mt)
#pragma unroll
          for (int r = 0; r < 4; ++r) mx = fmaxf(mx, s[mt][n2][r]);
        mx = fmaxf(mx, __shfl_xor(mx, 16, 64));
        mx = fmaxf(mx, __shfl_xor(mx, 32, 64));
        float mn = fmaxf(m_s[n2], mx);
        alpha[n2] = __expf(m_s[n2] - mn);
        m_s[n2] = mn;
        float sum = 0.f;
        int q = n2 * 16 + lr;
#pragma unroll
        for (int mt = 0; mt < 4; ++mt) {
          ushort4 pk;
          float p0 = __expf(s[mt][n2][0] - mn);
          float p1 = __expf(s[mt][n2][1] - mn);
          float p2 = __expf(s[mt][n2][2] - mn);
          float p3 = __expf(s[mt][n2][3] - mn);
          sum += (p0 + p1) + (p2 + p3);
          pk.x = f2b(p0); pk.y = f2b(p1); pk.z = f2b(p2); pk.w = f2b(p3);
          *reinterpret_cast<ushort4*>(&Ps[wave][q * 72 + mt * 16 + lq * 4]) = pk;
        }
        sum += __shfl_xor(sum, 16, 64);
        sum += __shfl_xor(sum, 32, 64);
        l_s[n2] = l_s[n2] * alpha[n2] + sum;
      }

      if (lq == 0) {
        Al[wave][lr] = alpha[0];
        Al[wave][16 + lr] = alpha[1];
      }
#pragma unroll
      for (int q2 = 0; q2 < 2; ++q2) {
        f32x4 av = *reinterpret_cast<const f32x4*>(&Al[wave][q2 * 16 + lq * 4]);
#pragma unroll
        for (int r = 0; r < 4; ++r)
#pragma unroll
          for (int dt = 0; dt < 8; ++dt) o[q2][dt][r] *= av[r];
      }

#pragma unroll
      for (int kh = 0; kh < 2; ++kh) {
        bf16x8 ap[2];
#pragma unroll
        for (int q2 = 0; q2 < 2; ++q2)
          ap[q2] = *reinterpret_cast<const bf16x8*>(
              &Ps[wave][(q2 * 16 + lr) * 72 + kh * 32 + lq * 8]);
#pragma unroll
        for (int dt = 0; dt < 8; ++dt) {
          int d = dt * 16 + lr;
          int slot = (kh * 4 + lq + d) & 7;
          bf16x8 bv = *reinterpret_cast<const bf16x8*>(&Vs[d * 64 + slot * 8]);
#pragma unroll
          for (int q2 = 0; q2 < 2; ++q2)
            o[q2][dt] = __builtin_amdgcn_mfma_f32_16x16x32_bf16(ap[q2], bv, o[q2][dt], 0, 0, 0);
        }
      }
    }

    if (lq == 0) {
      Al[wave][lr] = l_s[0];
      Al[wave][16 + lr] = l_s[1];
    }
#pragma unroll
    for (int q2 = 0; q2 < 2; ++q2) {
      f32x4 lv = *reinterpret_cast<const f32x4*>(&Al[wave][q2 * 16 + lq * 4]);
#pragma unroll
      for (int r = 0; r < 4; ++r) {
        float inv = 1.0f / lv[r];
        int q = qbase + q2 * 16 + lq * 4 + r;
        u16* yp = Y + (((long long)b * T_SEQ + q) * NHEAD + h) * HDIM;
#pragma unroll
        for (int dt = 0; dt < 8; ++dt)
          yp[dt * 16 + lr] = f2b(o[q2][dt][r] * inv);
      }
    }
  }
}

extern "C" void kernel_launch(void* const* d_in, const int* in_sizes, int n_in,
                              void* d_out, int out_size, void* d_ws, size_t ws_size,
                              hipStream_t stream) {
  (void)in_sizes; (void)n_in; (void)out_size; (void)ws_size;
  const float* x  = (const float*)d_in[0];
  const float* wq = (const float*)d_in[1];
  const float* wk = (const float*)d_in[2];
  const float* wv = (const float*)d_in[3];
  const float* wo = (const float*)d_in[4];
  float* out = (float*)d_out;

  char* ws = (char*)d_ws;
  size_t off = 0;
  auto alloc = [&](size_t bytes) {
    char* p = ws + off;
    off += (bytes + 255) & ~(size_t)255;
    return p;
  };
  const size_t NTOK = (size_t)BATCH * T_SEQ;
  const size_t XE = NTOK * E_DIM;
  const size_t WE = (size_t)E_DIM * E_DIM;

  u16* xb  = (u16*)alloc(XE * 2);
  u16* wqt = (u16*)alloc(WE * 2);
  u16* wkt = (u16*)alloc(WE * 2);
  u16* wvt = (u16*)alloc(WE * 2);
  u16* wot = (u16*)alloc(WE * 2);
  u16* Qb  = (u16*)alloc(XE * 2);
  u16* Kb  = (u16*)alloc(XE * 2);
  u16* Vb  = (u16*)alloc(XE * 2);
  u16* Vt  = (u16*)alloc(XE * 2);
  u16* Yb  = (u16*)alloc(XE * 2);
  float* cost = (float*)alloc((size_t)T_SEQ * 64 * 4);
  float* sint = (float*)alloc((size_t)T_SEQ * 64 * 4);

  convert_f32_bf16<<<XE / 1024, 256, 0, stream>>>(x, xb, (int)XE);
  dim3 gw(E_DIM / 64, E_DIM / 64);
  convt_w_k<<<gw, 256, 0, stream>>>(wq, wqt);
  convt_w_k<<<gw, 256, 0, stream>>>(wk, wkt);
  convt_w_k<<<gw, 256, 0, stream>>>(wv, wvt);
  convt_w_k<<<gw, 256, 0, stream>>>(wo, wot);
  rope_tables_k<<<(T_SEQ * 64) / 256, 256, 0, stream>>>(cost, sint);

  dim3 gq(E_DIM / 128, NTOK / 128, 3);
  gemm_bt_k<<<gq, 256, 0, stream>>>(xb, wqt, wkt, wvt, Qb, Kb, Vb, nullptr,
                                    (int)NTOK, E_DIM, E_DIM);

  rope_rms_k<<<(unsigned)(NTOK * NHEAD / 4) * 2, 256, 0, stream>>>(Qb, Kb, cost, sint);

  dim3 gt(T_SEQ / 64, HDIM / 64, BATCH * NHEAD);
  transpose_v_k<<<gt, 256, 0, stream>>>(Vb, Vt);

  dim3 ga(NQT / 2, BATCH * NHEAD);
  attn_k<<<ga, 256, 0, stream>>>(Qb, Kb, Vt, Yb);

  dim3 go(E_DIM / 128, NTOK / 128, 1);
  gemm_bt_k<<<go, 256, 0, stream>>>(Yb, wot, wot, wot, nullptr, nullptr, nullptr, out,
                                    (int)NTOK, E_DIM, E_DIM);
}